// Round 8
// baseline (490.000 us; speedup 1.0000x reference)
//
#include <hip/hip_runtime.h>
#include <cmath>

#define H1    64
#define T1    50
#define T2    100
#define BATCH 8192
#define NTILE 512        // global 16-sample tiles

typedef __attribute__((ext_vector_type(8))) short s16x8;
typedef __attribute__((ext_vector_type(4))) float f32x4;

#define MFMA16(a,b,c) __builtin_amdgcn_mfma_f32_16x16x32_bf16(a,b,c,0,0,0)

#define S_SIG  (-1.4426950408889634f)   // -1/ln2 : sigmoid gates (i,f,o)
#define S_TANH ( 2.8853900817779268f)   // +2/ln2 : tanh gate (g)

// ---- workspace byte offsets ----
#define OFF_FC1T  ((size_t)0)                                   // fp32 T1*BATCH
#define OFF_XF    ((size_t)1638400)                             // ushort T1*4*NTILE*64*8
#define OFF_WA1   ((size_t)(1638400 + 104857600))               // ushort 32768
#define OFF_WA2HH (OFF_WA1 + 65536)                             // ushort 32768
#define OFF_WA2IH (OFF_WA2HH + 65536)                           // ushort 65536
#define OFF_PART  (OFF_WA2IH + 131072)                          // fp32 2*T2*BATCH
#define OFF_BS    (OFF_PART + 6553600)                          // fp32 2*256 prescaled bias

// wave-local LDS ordering: DS completes in-order per wave; asm pins compiler order
#define LGKM0() asm volatile("s_waitcnt lgkmcnt(0)" ::: "memory")

__device__ __forceinline__ float rcp_(float x) { return __builtin_amdgcn_rcpf(x); }
__device__ __forceinline__ float exp2_(float x) {
#if __has_builtin(__builtin_amdgcn_exp2f)
    return __builtin_amdgcn_exp2f(x);
#else
    return exp2f(x);
#endif
}
__device__ __forceinline__ float sigp_(float e)  { return rcp_(1.f + exp2_(e)); }
__device__ __forceinline__ float tanhp_(float e) { return 1.f - 2.f * rcp_(1.f + exp2_(e)); }
__device__ __forceinline__ float tanhc_(float c) { return tanhp_(S_TANH * c); }
__device__ __forceinline__ float tanh_(float x)  { return tanhc_(x); }

__device__ __forceinline__ unsigned short bf16_rne(float x) {
    unsigned int u = __float_as_uint(x);
    u += 0x7fffu + ((u >> 16) & 1u);
    return (unsigned short)(u >> 16);
}
__device__ __forceinline__ float bf16f(unsigned short h) {
    return __uint_as_float(((unsigned int)h) << 16);
}

// ---------------- k_pre: weight frags (prescaled) + bias table + fc1 ----------------
__global__ __launch_bounds__(256) void k_pre(
    const float* __restrict__ whh1f, const float* __restrict__ whh1b,
    const float* __restrict__ whh2f, const float* __restrict__ whh2b,
    const float* __restrict__ wih2f, const float* __restrict__ wih2b,
    const float* __restrict__ b2f,   const float* __restrict__ b2b,
    const float* __restrict__ x, const float* __restrict__ fc1w,
    const float* __restrict__ fc1b,
    unsigned short* __restrict__ WA1, unsigned short* __restrict__ WA2HH,
    unsigned short* __restrict__ WA2IH, float* __restrict__ fc1T,
    float* __restrict__ BS)
{
    __shared__ float wls[1000];
    __shared__ float bls[50];
    int tid = threadIdx.x;
    int blk = blockIdx.x;
    if (blk < 64) {
        int i = blk * 256 + tid;                    // 16384 slots
        if (i < 8192) {
            int a   = i >> 12;                      // 0: layer1 whh, 1: layer2 whh
            int r   = i & 4095;
            int dir = r >> 11, rem = r & 2047;
            int mt  = rem >> 7, rem2 = rem & 127;
            int kk  = rem2 >> 6, l = rem2 & 63;
            const float* s_ = a ? (dir ? whh2b : whh2f) : (dir ? whh1b : whh1f);
            unsigned short* d_ = a ? WA2HH : WA1;
            int gate = mt * 16 + (l & 15);
            float sc = ((gate >> 6) == 2) ? S_TANH : S_SIG;
            int k0   = kk * 32 + (l >> 4) * 8;
            const float* p = s_ + gate * 64 + k0;
            unsigned short* q = d_ + (size_t)r * 8;
#pragma unroll
            for (int j = 0; j < 8; ++j) q[j] = bf16_rne(p[j] * sc);
        } else {
            int r   = i - 8192;                     // layer2 wih, 8192 slots
            int dir = r >> 12, rem = r & 4095;
            int mt  = rem >> 8, rem2 = rem & 255;
            int kk  = rem2 >> 6, l = rem2 & 63;
            const float* s_ = dir ? wih2b : wih2f;
            int gate = mt * 16 + (l & 15);
            float sc = ((gate >> 6) == 2) ? S_TANH : S_SIG;
            int k0   = kk * 32 + (l >> 4) * 8;
            const float* p = s_ + gate * 128 + k0;
            unsigned short* q = WA2IH + (size_t)r * 8;
#pragma unroll
            for (int j = 0; j < 8; ++j) q[j] = bf16_rne(p[j] * sc);
        }
    } else if (blk < 96) {
        // fc1
        for (int i = tid; i < 1000; i += 256) wls[i] = fc1w[i];
        if (tid < 50) bls[tid] = fc1b[tid];
        __syncthreads();
        int bidx = (blk - 64) * 256 + tid;
        float xv[20];
#pragma unroll
        for (int i = 0; i < 20; ++i) xv[i] = x[bidx * 20 + i];
        for (int t = 0; t < T1; ++t) {
            float s = bls[t];
#pragma unroll
            for (int i = 0; i < 20; ++i) s += xv[i] * wls[t * 20 + i];
            fc1T[t * BATCH + bidx] = s;
        }
    } else {
        // prescaled layer-2 bias table: BS[dir*256 + m] = bias[m] * sc(m>>6)
        for (int i = tid; i < 512; i += 256) {
            int d = i >> 8, m = i & 255;
            const float* bb = d ? b2b : b2f;
            float sc = ((m >> 6) == 2) ? S_TANH : S_SIG;
            BS[i] = bb[m] * sc;
        }
    }
}

// ---------------- layer-1 BiLSTM: 1 wave = 16 samples x full 64-h, no loop barriers ----------------
__global__ __launch_bounds__(256, 1) void k_lstm1(
    const float* __restrict__ wih1f, const float* __restrict__ b1f,
    const float* __restrict__ wih1b, const float* __restrict__ b1b,
    const unsigned short* __restrict__ WA1,
    const float* __restrict__ fc1T,
    unsigned short* __restrict__ XF)
{
    __shared__ float x1s[T1][64];
    __shared__ unsigned short Hs[4][2][16][64];   // [wave][hi/lo][col][k^swz] 16 KB
    int tid  = threadIdx.x;
    int lane = tid & 63;
    int wh   = __builtin_amdgcn_readfirstlane(tid >> 6);
    int quad = lane >> 4, col = lane & 15;
    int dir  = blockIdx.y, bx = blockIdx.x;
    int gtile = bx * 4 + wh;

    for (int i = tid; i < T1 * 64; i += 256)
        x1s[i >> 6][i & 63] = fc1T[(size_t)(i >> 6) * BATCH + bx * 64 + (i & 63)];

    const float* wih = dir ? wih1b : wih1f;
    const float* bia = dir ? b1b : b1f;
    f32x4 wvv[16], bvv[16];
#pragma unroll
    for (int mt = 0; mt < 16; ++mt) {
        float sc = ((mt >> 2) == 2) ? S_TANH : S_SIG;
#pragma unroll
        for (int r = 0; r < 4; ++r) {
            int G = mt * 16 + quad * 4 + r;
            wvv[mt][r] = wih[G] * sc;
            bvv[mt][r] = bia[G] * sc;
        }
    }
    s16x8 whhA[16][2];
#pragma unroll
    for (int mt = 0; mt < 16; ++mt)
#pragma unroll
        for (int kk = 0; kk < 2; ++kk)
            whhA[mt][kk] = *(const s16x8*)(WA1 +
                ((size_t)((dir * 16 + mt) * 2 + kk) * 64 + lane) * 8);

    float cst[16];
#pragma unroll
    for (int i = 0; i < 16; ++i) cst[i] = 0.f;

    int xorv = (col & 7) << 3;
    unsigned short* Whi = &Hs[wh][0][col][0];
    unsigned short* Wlo = &Hs[wh][1][col][0];
    __syncthreads();                                 // x1s staged (only barrier)

    s16x8 hbh[2], hbl[2];
    for (int s = 0; s < T1; ++s) {
        int t = dir ? (T1 - 1 - s) : s;
        float xt = x1s[t][wh * 16 + col];
        f32x4 acc[16];
#pragma unroll
        for (int mt = 0; mt < 16; ++mt)
#pragma unroll
            for (int r = 0; r < 4; ++r)
                acc[mt][r] = bvv[mt][r] + wvv[mt][r] * xt;
        if (s) {
#pragma unroll
            for (int mt = 0; mt < 16; ++mt) {
                f32x4 a = acc[mt];
                a = MFMA16(whhA[mt][0], hbh[0], a);
                a = MFMA16(whhA[mt][1], hbh[1], a);
                a = MFMA16(whhA[mt][0], hbl[0], a);
                a = MFMA16(whhA[mt][1], hbl[1], a);
                acc[mt] = a;
            }
        }
#pragma unroll
        for (int mtl = 0; mtl < 4; ++mtl) {
            unsigned short hh[4], hl[4];
#pragma unroll
            for (int r = 0; r < 4; ++r) {
                float iv = acc[mtl][r],      fv = acc[4 + mtl][r];
                float gv = acc[8 + mtl][r],  ov = acc[12 + mtl][r];
                float cc = sigp_(fv) * cst[mtl * 4 + r] + sigp_(iv) * tanhp_(gv);
                cst[mtl * 4 + r] = cc;
                float h = sigp_(ov) * tanhc_(cc);
                hh[r] = bf16_rne(h);
                hl[r] = bf16_rne(h - bf16f(hh[r]));
            }
            uint2 vhi, vlo;
            vhi.x = (unsigned)hh[0] | ((unsigned)hh[1] << 16);
            vhi.y = (unsigned)hh[2] | ((unsigned)hh[3] << 16);
            vlo.x = (unsigned)hl[0] | ((unsigned)hl[1] << 16);
            vlo.y = (unsigned)hl[2] | ((unsigned)hl[3] << 16);
            int kb = (mtl * 16 + quad * 4) ^ xorv;
            *(uint2*)&Whi[kb] = vhi;
            *(uint2*)&Wlo[kb] = vlo;
        }
        LGKM0();
#pragma unroll
        for (int kk = 0; kk < 2; ++kk) {
            int kr = (kk * 32 + quad * 8) ^ xorv;
            hbh[kk] = *(const s16x8*)&Whi[kr];
            hbl[kk] = *(const s16x8*)&Wlo[kr];
        }
#pragma unroll
        for (int kk = 0; kk < 2; ++kk)
            *(s16x8*)(XF + ((((size_t)t * 4 + (dir * 2 + kk)) * NTILE + gtile) * 64 + lane) * 8) = hbh[kk];
    }
}

// ---------------- layer-2 BiLSTM: 1 wave = 16 samples, Wih in LDS, fused fc2, no loop barriers ----------------
__global__ __launch_bounds__(256, 1) void k_lstm2(
    const float* __restrict__ BS,
    const float* __restrict__ fc2w,
    const unsigned short* __restrict__ WA2HH,
    const unsigned short* __restrict__ WA2IH,
    const unsigned short* __restrict__ XF,
    float* __restrict__ part)
{
    __shared__ unsigned short wAl[16][4][64][8];   // 64 KB Wih A-frags (this dir)
    __shared__ unsigned short Hs[4][2][16][64];    // 16 KB transform scratch
    __shared__ float bsl[256];                     // prescaled bias (this dir)
    int tid  = threadIdx.x;
    int lane = tid & 63;
    int wh   = __builtin_amdgcn_readfirstlane(tid >> 6);
    int quad = lane >> 4, col = lane & 15;
    int dir  = blockIdx.y, bx = blockIdx.x;
    int gtile = bx * 4 + wh;

    {   // stage Wih A-fragments (our dir) into LDS
        const uint4* src = (const uint4*)(WA2IH + (size_t)dir * 32768);
        uint4* dst = (uint4*)&wAl[0][0][0][0];
        for (int i = tid; i < 4096; i += 256) dst[i] = src[i];
    }
    bsl[tid] = BS[dir * 256 + tid];

    float f2v[16];
#pragma unroll
    for (int mtl = 0; mtl < 4; ++mtl)
#pragma unroll
        for (int r = 0; r < 4; ++r)
            f2v[mtl * 4 + r] = fc2w[dir * 64 + mtl * 16 + quad * 4 + r];

    s16x8 whhA[16][2];
#pragma unroll
    for (int mt = 0; mt < 16; ++mt)
#pragma unroll
        for (int kk = 0; kk < 2; ++kk)
            whhA[mt][kk] = *(const s16x8*)(WA2HH +
                ((size_t)((dir * 16 + mt) * 2 + kk) * 64 + lane) * 8);

    float cst[16];
#pragma unroll
    for (int i = 0; i < 16; ++i) cst[i] = 0.f;

    int xorv = (col & 7) << 3;
    unsigned short* Whi = &Hs[wh][0][col][0];
    unsigned short* Wlo = &Hs[wh][1][col][0];

#define XBLOAD(TP)                                                              \
    _Pragma("unroll")                                                           \
    for (int kk2 = 0; kk2 < 4; ++kk2)                                           \
        xbH[kk2] = *(const s16x8*)(XF +                                         \
            ((((size_t)(TP) * 4 + kk2) * NTILE + gtile) * 64 + lane) * 8);

#define IPROJ(DST)                                                              \
    _Pragma("unroll")                                                           \
    for (int mt = 0; mt < 16; ++mt) {                                           \
        f32x4 a = *(const f32x4*)&bsl[mt * 16 + quad * 4];                      \
        _Pragma("unroll")                                                       \
        for (int kk2 = 0; kk2 < 4; ++kk2) {                                     \
            s16x8 wa = *(const s16x8*)&wAl[mt][kk2][lane][0];                   \
            a = MFMA16(wa, xbH[kk2], a);                                        \
        }                                                                       \
        DST[mt] = a;                                                            \
    }

#define RECUR()                                                                 \
    _Pragma("unroll")                                                           \
    for (int mt = 0; mt < 16; ++mt) {                                           \
        f32x4 a = xaccC[mt];                                                    \
        a = MFMA16(whhA[mt][0], hbh[0], a);                                     \
        a = MFMA16(whhA[mt][1], hbh[1], a);                                     \
        a = MFMA16(whhA[mt][0], hbl[0], a);                                     \
        a = MFMA16(whhA[mt][1], hbl[1], a);                                     \
        acc[mt] = a;                                                            \
    }

#define ACT2(T2IDX)                                                             \
    {                                                                           \
        float pacc = 0.f;                                                       \
        _Pragma("unroll")                                                       \
        for (int mtl = 0; mtl < 4; ++mtl) {                                     \
            unsigned short hh[4], hl[4];                                        \
            _Pragma("unroll")                                                   \
            for (int r = 0; r < 4; ++r) {                                       \
                float iv = acc[mtl][r],      fv = acc[4 + mtl][r];              \
                float gv = acc[8 + mtl][r],  ov = acc[12 + mtl][r];             \
                float cc = sigp_(fv) * cst[mtl * 4 + r] + sigp_(iv) * tanhp_(gv); \
                cst[mtl * 4 + r] = cc;                                          \
                float h = sigp_(ov) * tanhc_(cc);                               \
                pacc += f2v[mtl * 4 + r] * h;                                   \
                unsigned u  = __float_as_uint(h);                               \
                unsigned uh = u & 0xFFFF0000u;                                  \
                hh[r] = (unsigned short)(uh >> 16);                             \
                hl[r] = bf16_rne(h - __uint_as_float(uh));                      \
            }                                                                   \
            uint2 vhi, vlo;                                                     \
            vhi.x = (unsigned)hh[0] | ((unsigned)hh[1] << 16);                  \
            vhi.y = (unsigned)hh[2] | ((unsigned)hh[3] << 16);                  \
            vlo.x = (unsigned)hl[0] | ((unsigned)hl[1] << 16);                  \
            vlo.y = (unsigned)hl[2] | ((unsigned)hl[3] << 16);                  \
            int kb = (mtl * 16 + quad * 4) ^ xorv;                              \
            *(uint2*)&Whi[kb] = vhi;                                            \
            *(uint2*)&Wlo[kb] = vlo;                                            \
        }                                                                       \
        pacc += __shfl_xor(pacc, 16);                                           \
        pacc += __shfl_xor(pacc, 32);                                           \
        LGKM0();                                                                \
        _Pragma("unroll")                                                       \
        for (int kk = 0; kk < 2; ++kk) {                                        \
            int kr = (kk * 32 + quad * 8) ^ xorv;                               \
            hbh[kk] = *(const s16x8*)&Whi[kr];                                  \
            hbl[kk] = *(const s16x8*)&Wlo[kr];                                  \
        }                                                                       \
        if (lane < 16)                                                          \
            part[((size_t)(dir * T2 + (T2IDX))) * BATCH + gtile * 16 + lane] = pacc; \
    }

    // pair-0 X-frags, then projection after the single staging barrier
    s16x8 xbH[4];
    {
        int tp0 = dir ? (T1 - 1) : 0;
        XBLOAD(tp0);
    }
    __syncthreads();                                 // wAl/bsl staged (only barrier)
    f32x4 xaccC[16], xaccN[16];
    IPROJ(xaccC);
    {
        int tp1 = dir ? (T1 - 2) : 1;
        XBLOAD(tp1);
    }

    s16x8 hbh[2], hbl[2];
    for (int p = 0; p < 50; ++p) {
        f32x4 acc[16];
        int t2 = dir ? (T2 - 1 - 2 * p) : 2 * p;
        if (p) {
            RECUR();
        } else {
#pragma unroll
            for (int mt = 0; mt < 16; ++mt) acc[mt] = xaccC[mt];
        }
        ACT2(t2);

        t2 = dir ? (T2 - 2 - 2 * p) : (2 * p + 1);
        RECUR();
        IPROJ(xaccN);                                // next pair, independent of h
        {
            int q2  = (p + 2 <= 49) ? p + 2 : 49;
            int tp2 = dir ? (49 - q2) : q2;
            XBLOAD(tp2);
        }
        ACT2(t2);
#pragma unroll
        for (int mt = 0; mt < 16; ++mt) xaccC[mt] = xaccN[mt];
    }
#undef XBLOAD
#undef IPROJ
#undef RECUR
#undef ACT2
}

// ---------------- combine + tanh ----------------
__global__ __launch_bounds__(256) void k_fc2(const float* __restrict__ part,
                                             const float* __restrict__ fc2b,
                                             float* __restrict__ out) {
    int u = blockIdx.x * 256 + threadIdx.x;
    if (u >= BATCH * T2) return;
    int b = u / T2, t = u - b * T2;
    float p = part[(size_t)t * BATCH + b] + part[((size_t)T2 + t) * BATCH + b] + fc2b[0];
    out[u] = tanh_(p);
}

extern "C" void kernel_launch(void* const* d_in, const int* in_sizes, int n_in,
                              void* d_out, int out_size, void* d_ws, size_t ws_size,
                              hipStream_t stream) {
    const float* x      = (const float*)d_in[0];
    const float* fc1w   = (const float*)d_in[1];
    const float* fc1b   = (const float*)d_in[2];
    const float* r1wihf = (const float*)d_in[3];
    const float* r1whhf = (const float*)d_in[4];
    const float* r1bf   = (const float*)d_in[5];
    const float* r1wihb = (const float*)d_in[6];
    const float* r1whhb = (const float*)d_in[7];
    const float* r1bb   = (const float*)d_in[8];
    const float* r2wihf = (const float*)d_in[9];
    const float* r2whhf = (const float*)d_in[10];
    const float* r2bf   = (const float*)d_in[11];
    const float* r2wihb = (const float*)d_in[12];
    const float* r2whhb = (const float*)d_in[13];
    const float* r2bb   = (const float*)d_in[14];
    const float* fc2w   = (const float*)d_in[15];
    const float* fc2b   = (const float*)d_in[16];
    char* ws   = (char*)d_ws;
    float* out = (float*)d_out;

    float*          fc1T  = (float*)(ws + OFF_FC1T);
    unsigned short* XF    = (unsigned short*)(ws + OFF_XF);
    unsigned short* WA1   = (unsigned short*)(ws + OFF_WA1);
    unsigned short* WA2HH = (unsigned short*)(ws + OFF_WA2HH);
    unsigned short* WA2IH = (unsigned short*)(ws + OFF_WA2IH);
    float*          partp = (float*)(ws + OFF_PART);
    float*          BS    = (float*)(ws + OFF_BS);

    k_pre<<<97, 256, 0, stream>>>(r1whhf, r1whhb, r2whhf, r2whhb, r2wihf, r2wihb,
                                  r2bf, r2bb, x, fc1w, fc1b,
                                  WA1, WA2HH, WA2IH, fc1T, BS);
    dim3 gl(128, 2);
    k_lstm1<<<gl, 256, 0, stream>>>(r1wihf, r1bf, r1wihb, r1bb, WA1, fc1T, XF);
    k_lstm2<<<gl, 256, 0, stream>>>(BS, fc2w, WA2HH, WA2IH, XF, partp);
    k_fc2<<<(BATCH * T2 + 255) / 256, 256, 0, stream>>>(partp, fc2b, out);
}

// Round 9
// 441.712 us; speedup vs baseline: 1.1093x; 1.1093x over previous
//
#include <hip/hip_runtime.h>
#include <cmath>

#define H1    64
#define T1    50
#define T2    100
#define BATCH 8192
#define NTILE 512        // global 16-sample tiles

typedef __attribute__((ext_vector_type(8))) short s16x8;
typedef __attribute__((ext_vector_type(4))) float f32x4;

#define MFMA16(a,b,c) __builtin_amdgcn_mfma_f32_16x16x32_bf16(a,b,c,0,0,0)

#define S_SIG  (-1.4426950408889634f)   // -1/ln2 : sigmoid gates (i,f,o)
#define S_TANH ( 2.8853900817779268f)   // +2/ln2 : tanh gate (g)

// ---- workspace byte offsets ----
#define OFF_FC1T  ((size_t)0)                                   // fp32 T1*BATCH
#define OFF_XF    ((size_t)1638400)                             // ushort T1*4*NTILE*64*8
#define OFF_WA1   ((size_t)(1638400 + 104857600))               // ushort 32768
#define OFF_WA2HH (OFF_WA1 + 65536)                             // ushort 32768
#define OFF_WA2IH (OFF_WA2HH + 65536)                           // ushort 65536
#define OFF_PART  (OFF_WA2IH + 131072)                          // fp32 2*T2*BATCH
#define OFF_BS    (OFF_PART + 6553600)                          // fp32 2*256 prescaled bias

// wave-local LDS ordering: DS completes in-order per wave; asm pins compiler order
#define LGKM0() asm volatile("s_waitcnt lgkmcnt(0)" ::: "memory")

__device__ __forceinline__ float rcp_(float x) { return __builtin_amdgcn_rcpf(x); }
__device__ __forceinline__ float exp2_(float x) {
#if __has_builtin(__builtin_amdgcn_exp2f)
    return __builtin_amdgcn_exp2f(x);
#else
    return exp2f(x);
#endif
}
__device__ __forceinline__ float sigp_(float e)  { return rcp_(1.f + exp2_(e)); }
__device__ __forceinline__ float tanhp_(float e) { return 1.f - 2.f * rcp_(1.f + exp2_(e)); }
__device__ __forceinline__ float tanhc_(float c) { return tanhp_(S_TANH * c); }
__device__ __forceinline__ float tanh_(float x)  { return tanhc_(x); }

__device__ __forceinline__ unsigned short bf16_rne(float x) {
    unsigned int u = __float_as_uint(x);
    u += 0x7fffu + ((u >> 16) & 1u);
    return (unsigned short)(u >> 16);
}
__device__ __forceinline__ float bf16f(unsigned short h) {
    return __uint_as_float(((unsigned int)h) << 16);
}

// ---------------- k_pre: weight frags (prescaled) + bias table + fc1 ----------------
__global__ __launch_bounds__(256) void k_pre(
    const float* __restrict__ whh1f, const float* __restrict__ whh1b,
    const float* __restrict__ whh2f, const float* __restrict__ whh2b,
    const float* __restrict__ wih2f, const float* __restrict__ wih2b,
    const float* __restrict__ b2f,   const float* __restrict__ b2b,
    const float* __restrict__ x, const float* __restrict__ fc1w,
    const float* __restrict__ fc1b,
    unsigned short* __restrict__ WA1, unsigned short* __restrict__ WA2HH,
    unsigned short* __restrict__ WA2IH, float* __restrict__ fc1T,
    float* __restrict__ BS)
{
    __shared__ float wls[1000];
    __shared__ float bls[50];
    int tid = threadIdx.x;
    int blk = blockIdx.x;
    if (blk < 64) {
        int i = blk * 256 + tid;                    // 16384 slots
        if (i < 8192) {
            int a   = i >> 12;                      // 0: layer1 whh, 1: layer2 whh
            int r   = i & 4095;
            int dir = r >> 11, rem = r & 2047;
            int mt  = rem >> 7, rem2 = rem & 127;
            int kk  = rem2 >> 6, l = rem2 & 63;
            const float* s_ = a ? (dir ? whh2b : whh2f) : (dir ? whh1b : whh1f);
            unsigned short* d_ = a ? WA2HH : WA1;
            int gate = mt * 16 + (l & 15);
            float sc = ((gate >> 6) == 2) ? S_TANH : S_SIG;
            int k0   = kk * 32 + (l >> 4) * 8;
            const float* p = s_ + gate * 64 + k0;
            unsigned short* q = d_ + (size_t)r * 8;
#pragma unroll
            for (int j = 0; j < 8; ++j) q[j] = bf16_rne(p[j] * sc);
        } else {
            int r   = i - 8192;                     // layer2 wih, 8192 slots
            int dir = r >> 12, rem = r & 4095;
            int mt  = rem >> 8, rem2 = rem & 255;
            int kk  = rem2 >> 6, l = rem2 & 63;
            const float* s_ = dir ? wih2b : wih2f;
            int gate = mt * 16 + (l & 15);
            float sc = ((gate >> 6) == 2) ? S_TANH : S_SIG;
            int k0   = kk * 32 + (l >> 4) * 8;
            const float* p = s_ + gate * 128 + k0;
            unsigned short* q = WA2IH + (size_t)r * 8;
#pragma unroll
            for (int j = 0; j < 8; ++j) q[j] = bf16_rne(p[j] * sc);
        }
    } else if (blk < 96) {
        // fc1
        for (int i = tid; i < 1000; i += 256) wls[i] = fc1w[i];
        if (tid < 50) bls[tid] = fc1b[tid];
        __syncthreads();
        int bidx = (blk - 64) * 256 + tid;
        float xv[20];
#pragma unroll
        for (int i = 0; i < 20; ++i) xv[i] = x[bidx * 20 + i];
        for (int t = 0; t < T1; ++t) {
            float s = bls[t];
#pragma unroll
            for (int i = 0; i < 20; ++i) s += xv[i] * wls[t * 20 + i];
            fc1T[t * BATCH + bidx] = s;
        }
    } else {
        // prescaled layer-2 bias table: BS[dir*256 + m] = bias[m] * sc(m>>6)
        for (int i = tid; i < 512; i += 256) {
            int d = i >> 8, m = i & 255;
            const float* bb = d ? b2b : b2f;
            float sc = ((m >> 6) == 2) ? S_TANH : S_SIG;
            BS[i] = bb[m] * sc;
        }
    }
}

// ---------------- layer-1 BiLSTM: 1 wave = 16 samples x full h; pipelined, no barriers ----------------
__global__ __launch_bounds__(256, 1) void k_lstm1(
    const float* __restrict__ wih1f, const float* __restrict__ b1f,
    const float* __restrict__ wih1b, const float* __restrict__ b1b,
    const unsigned short* __restrict__ WA1,
    const float* __restrict__ fc1T,
    unsigned short* __restrict__ XF)
{
    __shared__ unsigned short Hs[4][2][16][64];   // [wave][hi/lo][col][k^swz] 16 KB
    int tid  = threadIdx.x;
    int lane = tid & 63;
    int wh   = __builtin_amdgcn_readfirstlane(tid >> 6);
    int quad = lane >> 4, col = lane & 15;
    int dir  = blockIdx.y, bx = blockIdx.x;
    int gtile = bx * 4 + wh;
    int samp  = bx * 64 + wh * 16 + col;

    const float* wih = dir ? wih1b : wih1f;
    const float* bia = dir ? b1b : b1f;
    f32x4 wvv[16], bvv[16];
#pragma unroll
    for (int mt = 0; mt < 16; ++mt) {
        float sc = ((mt >> 2) == 2) ? S_TANH : S_SIG;
#pragma unroll
        for (int r = 0; r < 4; ++r) {
            int G = mt * 16 + quad * 4 + r;
            wvv[mt][r] = wih[G] * sc;
            bvv[mt][r] = bia[G] * sc;
        }
    }
    s16x8 whhA[16][2];
#pragma unroll
    for (int mt = 0; mt < 16; ++mt)
#pragma unroll
        for (int kk = 0; kk < 2; ++kk)
            whhA[mt][kk] = *(const s16x8*)(WA1 +
                ((size_t)((dir * 16 + mt) * 2 + kk) * 64 + lane) * 8);

    float cst[16];
#pragma unroll
    for (int i = 0; i < 16; ++i) cst[i] = 0.f;

    int xorv = (col & 7) << 3;
    unsigned short* Whi = &Hs[wh][0][col][0];
    unsigned short* Wlo = &Hs[wh][1][col][0];

    s16x8 hbh[2], hbl[2];
    int tprev = 0;
    float xcur = fc1T[(size_t)(dir ? (T1 - 1) : 0) * BATCH + samp];

    for (int s = 0; s < T1; ++s) {
        int t = dir ? (T1 - 1 - s) : s;
        // acc init (independent of h; overlaps the lgkm wait on hb)
        f32x4 acc[16];
#pragma unroll
        for (int mt = 0; mt < 16; ++mt)
#pragma unroll
            for (int r = 0; r < 4; ++r)
                acc[mt][r] = bvv[mt][r] + wvv[mt][r] * xcur;
        if (s) {
            // 1) RECUR — the only thing that must wait on hb
#pragma unroll
            for (int mt = 0; mt < 16; ++mt) {
                f32x4 a = acc[mt];
                a = MFMA16(whhA[mt][0], hbh[0], a);
                a = MFMA16(whhA[mt][1], hbh[1], a);
                a = MFMA16(whhA[mt][0], hbl[0], a);
                a = MFMA16(whhA[mt][1], hbl[1], a);
                acc[mt] = a;
            }
            // 2) deferred XF store of h(tprev) — hb resolved by RECUR's wait
#pragma unroll
            for (int kk = 0; kk < 2; ++kk)
                *(s16x8*)(XF + ((((size_t)tprev * 4 + (dir * 2 + kk)) * NTILE + gtile) * 64 + lane) * 8) = hbh[kk];
        }
        // 3) prefetch next x (off-path)
        if (s < T1 - 1)
            xcur = fc1T[(size_t)(dir ? (T1 - 2 - s) : (s + 1)) * BATCH + samp];
        // 4) ACT: trans -> pack -> Hs write -> readback issue
#pragma unroll
        for (int mtl = 0; mtl < 4; ++mtl) {
            unsigned short hh[4], hl[4];
#pragma unroll
            for (int r = 0; r < 4; ++r) {
                float iv = acc[mtl][r],      fv = acc[4 + mtl][r];
                float gv = acc[8 + mtl][r],  ov = acc[12 + mtl][r];
                float cc = sigp_(fv) * cst[mtl * 4 + r] + sigp_(iv) * tanhp_(gv);
                cst[mtl * 4 + r] = cc;
                float h = sigp_(ov) * tanhc_(cc);
                hh[r] = bf16_rne(h);
                hl[r] = bf16_rne(h - bf16f(hh[r]));
            }
            uint2 vhi, vlo;
            vhi.x = (unsigned)hh[0] | ((unsigned)hh[1] << 16);
            vhi.y = (unsigned)hh[2] | ((unsigned)hh[3] << 16);
            vlo.x = (unsigned)hl[0] | ((unsigned)hl[1] << 16);
            vlo.y = (unsigned)hl[2] | ((unsigned)hl[3] << 16);
            int kb = (mtl * 16 + quad * 4) ^ xorv;
            *(uint2*)&Whi[kb] = vhi;
            *(uint2*)&Wlo[kb] = vlo;
        }
        LGKM0();
#pragma unroll
        for (int kk = 0; kk < 2; ++kk) {
            int kr = (kk * 32 + quad * 8) ^ xorv;
            hbh[kk] = *(const s16x8*)&Whi[kr];
            hbl[kk] = *(const s16x8*)&Wlo[kr];
        }
        tprev = t;
    }
    // tail: last step's h
#pragma unroll
    for (int kk = 0; kk < 2; ++kk)
        *(s16x8*)(XF + ((((size_t)tprev * 4 + (dir * 2 + kk)) * NTILE + gtile) * 64 + lane) * 8) = hbh[kk];
}

// ---------------- layer-2 BiLSTM: pipelined, fc2 via MFMA, no loop barriers ----------------
__global__ __launch_bounds__(256, 1) void k_lstm2(
    const float* __restrict__ BS,
    const float* __restrict__ fc2w,
    const unsigned short* __restrict__ WA2HH,
    const unsigned short* __restrict__ WA2IH,
    const unsigned short* __restrict__ XF,
    float* __restrict__ part)
{
    __shared__ unsigned short wAl[16][4][64][8];   // 64 KB Wih A-frags (this dir)
    __shared__ unsigned short Hs[4][2][16][64];    // 16 KB transform scratch
    __shared__ float bsl[256];                     // prescaled bias (this dir)
    int tid  = threadIdx.x;
    int lane = tid & 63;
    int wh   = __builtin_amdgcn_readfirstlane(tid >> 6);
    int quad = lane >> 4, col = lane & 15;
    int dir  = blockIdx.y, bx = blockIdx.x;
    int gtile = bx * 4 + wh;

    {   // stage Wih A-fragments (our dir) into LDS
        const uint4* src = (const uint4*)(WA2IH + (size_t)dir * 32768);
        uint4* dst = (uint4*)&wAl[0][0][0][0];
        for (int i = tid; i < 4096; i += 256) dst[i] = src[i];
    }
    bsl[tid] = BS[dir * 256 + tid];

    // fc2 weights as one-hot-row A-fragments: A[0][k] = f2[k], rows 1..15 zero
    s16x8 f2A[2];
#pragma unroll
    for (int kk = 0; kk < 2; ++kk)
#pragma unroll
        for (int j = 0; j < 8; ++j) {
            unsigned short v = bf16_rne(fc2w[dir * 64 + kk * 32 + quad * 8 + j]);
            ((short*)&f2A[kk])[j] = (col == 0) ? (short)v : (short)0;
        }

    s16x8 whhA[16][2];
#pragma unroll
    for (int mt = 0; mt < 16; ++mt)
#pragma unroll
        for (int kk = 0; kk < 2; ++kk)
            whhA[mt][kk] = *(const s16x8*)(WA2HH +
                ((size_t)((dir * 16 + mt) * 2 + kk) * 64 + lane) * 8);

    float cst[16];
#pragma unroll
    for (int i = 0; i < 16; ++i) cst[i] = 0.f;

    int xorv = (col & 7) << 3;
    unsigned short* Whi = &Hs[wh][0][col][0];
    unsigned short* Wlo = &Hs[wh][1][col][0];

#define XBLOAD(TP)                                                              \
    _Pragma("unroll")                                                           \
    for (int kk2 = 0; kk2 < 4; ++kk2)                                           \
        xb[kk2] = *(const s16x8*)(XF +                                          \
            ((((size_t)(TP) * 4 + kk2) * NTILE + gtile) * 64 + lane) * 8);

#define IPROJ()                                                                 \
    _Pragma("unroll")                                                           \
    for (int mt = 0; mt < 16; ++mt) {                                           \
        f32x4 a = *(const f32x4*)&bsl[mt * 16 + quad * 4];                      \
        _Pragma("unroll")                                                       \
        for (int kk2 = 0; kk2 < 4; ++kk2) {                                     \
            s16x8 wa = *(const s16x8*)&wAl[mt][kk2][lane][0];                   \
            a = MFMA16(wa, xb[kk2], a);                                         \
        }                                                                       \
        xaccC[mt] = a;                                                          \
    }

#define RECUR()                                                                 \
    _Pragma("unroll")                                                           \
    for (int mt = 0; mt < 16; ++mt) {                                           \
        f32x4 a = xaccC[mt];                                                    \
        a = MFMA16(whhA[mt][0], hbh[0], a);                                     \
        a = MFMA16(whhA[mt][1], hbh[1], a);                                     \
        a = MFMA16(whhA[mt][0], hbl[0], a);                                     \
        a = MFMA16(whhA[mt][1], hbl[1], a);                                     \
        acc[mt] = a;                                                            \
    }

// fc2 partial of h(TIDX): hb currently holds that h (resolved by RECUR's wait)
#define FC2STORE(TIDX)                                                          \
    {                                                                           \
        f32x4 pz; pz[0] = 0.f; pz[1] = 0.f; pz[2] = 0.f; pz[3] = 0.f;           \
        pz = MFMA16(f2A[0], hbh[0], pz);                                        \
        pz = MFMA16(f2A[1], hbh[1], pz);                                        \
        pz = MFMA16(f2A[0], hbl[0], pz);                                        \
        pz = MFMA16(f2A[1], hbl[1], pz);                                        \
        if (lane < 16)                                                          \
            part[((size_t)(dir * T2 + (TIDX))) * BATCH + gtile * 16 + lane] = pz[0]; \
    }

#define ACT()                                                                   \
    {                                                                           \
        _Pragma("unroll")                                                       \
        for (int mtl = 0; mtl < 4; ++mtl) {                                     \
            unsigned short hh[4], hl[4];                                        \
            _Pragma("unroll")                                                   \
            for (int r = 0; r < 4; ++r) {                                       \
                float iv = acc[mtl][r],      fv = acc[4 + mtl][r];              \
                float gv = acc[8 + mtl][r],  ov = acc[12 + mtl][r];             \
                float cc = sigp_(fv) * cst[mtl * 4 + r] + sigp_(iv) * tanhp_(gv); \
                cst[mtl * 4 + r] = cc;                                          \
                float h = sigp_(ov) * tanhc_(cc);                               \
                unsigned u  = __float_as_uint(h);                               \
                unsigned uh = u & 0xFFFF0000u;                                  \
                hh[r] = (unsigned short)(uh >> 16);                             \
                hl[r] = bf16_rne(h - __uint_as_float(uh));                      \
            }                                                                   \
            uint2 vhi, vlo;                                                     \
            vhi.x = (unsigned)hh[0] | ((unsigned)hh[1] << 16);                  \
            vhi.y = (unsigned)hh[2] | ((unsigned)hh[3] << 16);                  \
            vlo.x = (unsigned)hl[0] | ((unsigned)hl[1] << 16);                  \
            vlo.y = (unsigned)hl[2] | ((unsigned)hl[3] << 16);                  \
            int kb = (mtl * 16 + quad * 4) ^ xorv;                              \
            *(uint2*)&Whi[kb] = vhi;                                            \
            *(uint2*)&Wlo[kb] = vlo;                                            \
        }                                                                       \
        LGKM0();                                                                \
        _Pragma("unroll")                                                       \
        for (int kk = 0; kk < 2; ++kk) {                                        \
            int kr = (kk * 32 + quad * 8) ^ xorv;                               \
            hbh[kk] = *(const s16x8*)&Whi[kr];                                  \
            hbl[kk] = *(const s16x8*)&Wlo[kr];                                  \
        }                                                                       \
    }

    s16x8 xb[4];
    {   int tp0 = dir ? (T1 - 1) : 0; XBLOAD(tp0); }
    __syncthreads();                                 // wAl/bsl staged (only barrier)
    f32x4 xaccC[16];
    IPROJ();
    {   int tp1 = dir ? (T1 - 2) : 1; XBLOAD(tp1); }

    s16x8 hbh[2], hbl[2];
    int tprev = 0;
    for (int p = 0; p < 50; ++p) {
        f32x4 acc[16];
        // ---- even half-step ----
        if (p) {
            RECUR();
            FC2STORE(tprev);                         // h of previous odd step
        } else {
#pragma unroll
            for (int mt = 0; mt < 16; ++mt) acc[mt] = xaccC[mt];
        }
        int t2 = dir ? (T2 - 1 - 2 * p) : (2 * p);
        ACT();
        tprev = t2;
        // ---- odd half-step ----
        RECUR();
        FC2STORE(tprev);                             // h of even step
        t2 = dir ? (T2 - 2 - 2 * p) : (2 * p + 1);
        ACT();
        tprev = t2;
        // ---- off-path: next pair's projection + prefetch (1.5 steps of slack) ----
        IPROJ();
        {   int q2  = (p + 2 <= 49) ? p + 2 : 49;
            int tp2 = dir ? (49 - q2) : q2;
            XBLOAD(tp2); }
    }
    // tail: fc2 for the final odd step
    FC2STORE(tprev);
#undef XBLOAD
#undef IPROJ
#undef RECUR
#undef FC2STORE
#undef ACT
}

// ---------------- combine + tanh ----------------
__global__ __launch_bounds__(256) void k_fc2(const float* __restrict__ part,
                                             const float* __restrict__ fc2b,
                                             float* __restrict__ out) {
    int u = blockIdx.x * 256 + threadIdx.x;
    if (u >= BATCH * T2) return;
    int b = u / T2, t = u - b * T2;
    float p = part[(size_t)t * BATCH + b] + part[((size_t)T2 + t) * BATCH + b] + fc2b[0];
    out[u] = tanh_(p);
}

extern "C" void kernel_launch(void* const* d_in, const int* in_sizes, int n_in,
                              void* d_out, int out_size, void* d_ws, size_t ws_size,
                              hipStream_t stream) {
    const float* x      = (const float*)d_in[0];
    const float* fc1w   = (const float*)d_in[1];
    const float* fc1b   = (const float*)d_in[2];
    const float* r1wihf = (const float*)d_in[3];
    const float* r1whhf = (const float*)d_in[4];
    const float* r1bf   = (const float*)d_in[5];
    const float* r1wihb = (const float*)d_in[6];
    const float* r1whhb = (const float*)d_in[7];
    const float* r1bb   = (const float*)d_in[8];
    const float* r2wihf = (const float*)d_in[9];
    const float* r2whhf = (const float*)d_in[10];
    const float* r2bf   = (const float*)d_in[11];
    const float* r2wihb = (const float*)d_in[12];
    const float* r2whhb = (const float*)d_in[13];
    const float* r2bb   = (const float*)d_in[14];
    const float* fc2w   = (const float*)d_in[15];
    const float* fc2b   = (const float*)d_in[16];
    char* ws   = (char*)d_ws;
    float* out = (float*)d_out;

    float*          fc1T  = (float*)(ws + OFF_FC1T);
    unsigned short* XF    = (unsigned short*)(ws + OFF_XF);
    unsigned short* WA1   = (unsigned short*)(ws + OFF_WA1);
    unsigned short* WA2HH = (unsigned short*)(ws + OFF_WA2HH);
    unsigned short* WA2IH = (unsigned short*)(ws + OFF_WA2IH);
    float*          partp = (float*)(ws + OFF_PART);
    float*          BS    = (float*)(ws + OFF_BS);

    k_pre<<<97, 256, 0, stream>>>(r1whhf, r1whhb, r2whhf, r2whhb, r2wihf, r2wihb,
                                  r2bf, r2bb, x, fc1w, fc1b,
                                  WA1, WA2HH, WA2IH, fc1T, BS);
    dim3 gl(128, 2);
    k_lstm1<<<gl, 256, 0, stream>>>(r1wihf, r1bf, r1wihb, r1bb, WA1, fc1T, XF);
    k_lstm2<<<gl, 256, 0, stream>>>(BS, fc2w, WA2HH, WA2IH, XF, partp);
    k_fc2<<<(BATCH * T2 + 255) / 256, 256, 0, stream>>>(partp, fc2b, out);
}